// Round 10
// baseline (201.356 us; speedup 1.0000x reference)
//
#include <hip/hip_runtime.h>

// ---------------------------------------------------------------------------
// IntraModalityEnhance — fp32 in/out, bf16 MFMA internals.
// B=2, S=2048, D=1024, H=16, HD=64, E=1024, W=31 (+pos,+fsq keys = 33).
//
//  prep       : ONE launch — x/fsq/pos -> bf16  +  Wq/Wk/Wv/Wo transposes
//  proj_gemm  : ONE launch, 576 blocks x 512 threads, BM=128 x BN=256 with
//               N = K-half || V-half (K and V share the A-tile -> 2x MFMA per
//               barrier, A staged once for both).  Per-wave tile stays 64x64
//               (VGPR ~100, no per-wave occupancy cliff — R7's lesson).
//               K -> Kp row-major; V x-rows -> VpT[n][4096]; V fsq/pos rows
//               -> Vd row-major; Q -> Qp (Q blocks use WqT for both halves).
//  attn_tile  : block=(b,h,32 s); DMA staging, MFMA QK^T/PV, 35KB -> 4 blk/CU
//  out_gemm   : BM=64, 512 blocks, linear mapping -> d_out fp32
// ---------------------------------------------------------------------------

typedef __attribute__((ext_vector_type(8))) short bf16x8;
typedef __attribute__((ext_vector_type(4))) float f32x4;
typedef unsigned short u16;
typedef unsigned int u32;
typedef unsigned long long u64;

__device__ __forceinline__ float bf2f(u16 u) {
  union { u32 i; float f; } v; v.i = ((u32)u) << 16; return v.f;
}
__device__ __forceinline__ u16 f2bf(float f) {
  union { float f; u32 i; } v; v.f = f;
  u32 r = v.i + 0x7fffu + ((v.i >> 16) & 1u);
  return (u16)(r >> 16);
}
__device__ __forceinline__ float2 unpk(u32 u) {
  union { u32 i; float f; } lo, hi;
  lo.i = u << 16; hi.i = u & 0xffff0000u;
  return make_float2(lo.f, hi.f);
}
__device__ __forceinline__ float dot8(uint4 a, uint4 b) {
  float s = 0.f;
  { float2 x = unpk(a.x), y = unpk(b.x); s += x.x*y.x + x.y*y.y; }
  { float2 x = unpk(a.y), y = unpk(b.y); s += x.x*y.x + x.y*y.y; }
  { float2 x = unpk(a.z), y = unpk(b.z); s += x.x*y.x + x.y*y.y; }
  { float2 x = unpk(a.w), y = unpk(b.w); s += x.x*y.x + x.y*y.y; }
  return s;
}
__device__ __forceinline__ void gload_lds16(const u16* g, u16* l) {
  __builtin_amdgcn_global_load_lds((const __attribute__((address_space(1))) void*)(g),
                                   (__attribute__((address_space(3))) void*)(l),
                                   16, 0, 0);
}
__device__ __forceinline__ uint4 pack8(float4 a, float4 b) {
  union { u16 h[8]; uint4 q; } u;
  u.h[0] = f2bf(a.x); u.h[1] = f2bf(a.y); u.h[2] = f2bf(a.z); u.h[3] = f2bf(a.w);
  u.h[4] = f2bf(b.x); u.h[5] = f2bf(b.y); u.h[6] = f2bf(b.z); u.h[7] = f2bf(b.w);
  return u.q;
}

// ---------------------------------------------------------------------------
__device__ __forceinline__ void transpose_body(const float* src, u16* dst,
                                               int R, int C, int r0, int c0) {
  __shared__ u16 tile[64][72];
  int t = threadIdx.x;
#pragma unroll
  for (int i = 0; i < 16; ++i) {
    int idx = i * 256 + t;
    int r = idx >> 6, c = idx & 63;
    tile[r][c] = f2bf(src[(size_t)(r0 + r) * C + (c0 + c)]);
  }
  __syncthreads();
#pragma unroll
  for (int i = 0; i < 16; ++i) {
    int idx = i * 256 + t;
    int c = idx >> 6, r = idx & 63;
    dst[(size_t)(c0 + c) * R + (r0 + r)] = tile[r][c];
  }
}

// ONE launch: blocks 0..4095 convert x/fsq/pos; 4096..5119 transpose weights.
__global__ __launch_bounds__(256) void prep(const float* __restrict__ x,
                                            const float* __restrict__ fsq,
                                            const float* __restrict__ pos,
                                            const float* __restrict__ Wq,
                                            const float* __restrict__ Wk,
                                            const float* __restrict__ Wv,
                                            const float* __restrict__ Wo,
                                            u16* __restrict__ xb,
                                            u16* __restrict__ fsqb,
                                            u16* __restrict__ posb,
                                            u16* __restrict__ WqT,
                                            u16* __restrict__ WkT,
                                            u16* __restrict__ WvT,
                                            u16* __restrict__ WoT) {
  int bid = blockIdx.x;
  if (bid < 4096) {
    int i = bid * 256 + threadIdx.x;
    const float* src; u16* dst; int off;
    if (i < 524288)      { src = x;   dst = xb;   off = i; }
    else if (i < 786432) { src = fsq; dst = fsqb; off = i - 524288; }
    else                 { src = pos; dst = posb; off = i - 786432; }
    float4 a = ((const float4*)src)[2 * off];
    float4 b = ((const float4*)src)[2 * off + 1];
    ((uint4*)dst)[off] = pack8(a, b);
  } else {
    int id = bid - 4096;
    int z = id >> 8, rest = id & 255;
    int xx = rest & 15, yy = rest >> 4;
    if (z < 3) {
      const float* s = (z == 0) ? Wq : (z == 1) ? Wk : Wv;
      u16* d = (z == 0) ? WqT : (z == 1) ? WkT : WvT;
      size_t off = (size_t)xx * 65536;    // head * 1024 * 64
      transpose_body(s + off, d + off, 1024, 64, yy * 64, 0);
    } else {
      transpose_body(Wo, WoT, 1024, 1024, yy * 64, xx * 64);
    }
  }
}

// ---------------------------------------------------------------------------
// XOR-swizzled LDS helpers (16B chunk granularity; conflict-free frag reads).
// ---------------------------------------------------------------------------
__device__ __forceinline__ int swz(int R, int c) {   // u16 index of 16B chunk
  return (R * 8 + (c ^ (R & 7))) * 8;
}

// ---------------------------------------------------------------------------
// proj_gemm: 512 threads, BM=128 x BN=256 (N = two 128-col halves).
// blocks 0..511: K/V over A=[xb;fsqb;posb] (tm=bid>>3, tn=bid&7):
//   half A: Kp cols tn*128..; half B: V cols tn*128.. (VpT or Vd by tm)
// blocks 512..575: Q over fsqb (tm=q>>2, 256-col tile tn4=q&3 of Qp).
// Waves: 8; wave>>2 = m-half, wave&3 = n-quarter; 64x64 per wave, MT=4.
// Per k0-iter: A(128x64)+B(256x64) staged (6 DMA/thread), 256 MFMA/block.
// ---------------------------------------------------------------------------
__global__ __launch_bounds__(512) void proj_gemm(const u16* __restrict__ xb,
                                                 const u16* __restrict__ fsqb,
                                                 const u16* __restrict__ posb,
                                                 const u16* __restrict__ WkT,
                                                 const u16* __restrict__ WvT,
                                                 const u16* __restrict__ WqT,
                                                 const float* __restrict__ bk,
                                                 const float* __restrict__ bv,
                                                 const float* __restrict__ bq,
                                                 u16* __restrict__ Kp,
                                                 u16* __restrict__ VpT,
                                                 u16* __restrict__ Vd,
                                                 u16* __restrict__ Qp) {
  __shared__ u16 As[128 * 64];   // 16 KB
  __shared__ u16 Bs[256 * 64];   // 32 KB

  const int bid = blockIdx.x;
  const int t = threadIdx.x, lane = t & 63, wave = t >> 6;   // wave 0..7
  const int row16 = lane & 15, quad = lane >> 4;
  const int l8 = lane >> 3;
  const int cswz = (lane & 7) ^ l8;

  // ---- block decode ----
  const u16 *Ap, *BTa, *BTb;
  const float *biasA, *biasB;
  u16 *C1, *C2rm;                 // row-major outputs (stride 1024)
  int c1_noff, c2_noff;
  bool c2_t = false;              // C2 transposed (VpT)?
  int tmb = 0;                    // tile_m*128 (for VpT addressing)

  if (bid < 512) {
    int tm = bid >> 3, tn = bid & 7;
    if (tm < 32)      Ap = xb   + (size_t)tm * 131072;
    else if (tm < 48) Ap = fsqb + (size_t)(tm - 32) * 131072;
    else              Ap = posb + (size_t)(tm - 48) * 131072;
    BTa = WkT + (size_t)(tn * 128) * 1024;
    BTb = WvT + (size_t)(tn * 128) * 1024;
    biasA = bk; biasB = bv;
    C1 = Kp + (size_t)tm * 131072; c1_noff = tn * 128;
    c2_noff = tn * 128;
    if (tm < 32) { c2_t = true; tmb = tm * 128; C2rm = nullptr; }
    else         { C2rm = Vd + (size_t)(tm - 32) * 131072; }
  } else {
    int q = bid - 512;
    int tm = q >> 2, tn4 = q & 3;
    Ap  = fsqb + (size_t)tm * 131072;
    BTa = WqT + (size_t)(tn4 * 256) * 1024;
    BTb = WqT + (size_t)(tn4 * 256 + 128) * 1024;
    biasA = bq; biasB = bq;
    C1 = Qp + (size_t)tm * 131072;  c1_noff = tn4 * 256;
    C2rm = C1;                      c2_noff = tn4 * 256 + 128;
  }

  const int wm = (wave >> 2) * 64, wn = (wave & 3) * 64;
  f32x4 acc[4][4] = {};

  for (int k0 = 0; k0 < 1024; k0 += 64) {
    __syncthreads();
    // A: wave stages rows wave*16 .. +15
#pragma unroll
    for (int j = 0; j < 2; ++j) {
      int r = wave * 16 + j * 8 + l8;
      gload_lds16(Ap + (size_t)r * 1024 + k0 + cswz * 8,
                  &As[wave * 1024 + j * 512]);
    }
    // B: wave stages rows wave*32 .. +31 (waves 0-3 -> BTa, 4-7 -> BTb)
    const u16* Bsrc = (wave < 4) ? BTa : BTb;
    const int rb = (wave & 3) * 32;
#pragma unroll
    for (int j = 0; j < 4; ++j) {
      int r = rb + j * 8 + l8;
      gload_lds16(Bsrc + (size_t)r * 1024 + k0 + cswz * 8,
                  &Bs[wave * 2048 + j * 512]);
    }
    __syncthreads();

#pragma unroll
    for (int kb = 0; kb < 2; ++kb) {
      bf16x8 a_frag[4], b_frag[4];
#pragma unroll
      for (int i = 0; i < 4; ++i)
        a_frag[i] = *(const bf16x8*)&As[swz(wm + i * 16 + row16, kb * 4 + quad)];
#pragma unroll
      for (int j = 0; j < 4; ++j)
        b_frag[j] = *(const bf16x8*)&Bs[swz(wn + j * 16 + row16, kb * 4 + quad)];
#pragma unroll
      for (int i = 0; i < 4; ++i)
#pragma unroll
        for (int j = 0; j < 4; ++j)
          acc[i][j] = __builtin_amdgcn_mfma_f32_16x16x32_bf16(
              a_frag[i], b_frag[j], acc[i][j], 0, 0, 0);
    }
  }

  // ---- epilogue (wave-uniform half select); C/D: col=lane&15, row=quad*4+r
  if (wn < 128) {
#pragma unroll
    for (int j = 0; j < 4; ++j) {
      int n = c1_noff + wn + j * 16 + row16;
      float bb = biasA[n];
#pragma unroll
      for (int i = 0; i < 4; ++i) {
        int m0 = wm + i * 16 + quad * 4;
#pragma unroll
        for (int r = 0; r < 4; ++r)
          C1[(size_t)(m0 + r) * 1024 + n] = f2bf(acc[i][j][r] + bb);
      }
    }
  } else if (c2_t) {
#pragma unroll
    for (int j = 0; j < 4; ++j) {
      int nv = c2_noff + (wn - 128) + j * 16 + row16;
      float bb = biasB[nv];
#pragma unroll
      for (int i = 0; i < 4; ++i) {
        int m0 = wm + i * 16 + quad * 4;
        union { u16 h[4]; u64 q; } o;
#pragma unroll
        for (int r = 0; r < 4; ++r) o.h[r] = f2bf(acc[i][j][r] + bb);
        *(u64*)(VpT + (size_t)nv * 4096 + tmb + m0) = o.q;
      }
    }
  } else {
#pragma unroll
    for (int j = 0; j < 4; ++j) {
      int nv = c2_noff + (wn - 128) + j * 16 + row16;
      float bb = biasB[nv];
#pragma unroll
      for (int i = 0; i < 4; ++i) {
        int m0 = wm + i * 16 + quad * 4;
#pragma unroll
        for (int r = 0; r < 4; ++r)
          C2rm[(size_t)(m0 + r) * 1024 + nv] = f2bf(acc[i][j][r] + bb);
      }
    }
  }
}

// ---------------------------------------------------------------------------
// out_gemm: BM=64, BN=128, BK=64 (unchanged from R9).
// ---------------------------------------------------------------------------
__global__ __launch_bounds__(256) void out_gemm(const u16* __restrict__ Att,
                                                const u16* __restrict__ WoT,
                                                const float* __restrict__ bo,
                                                float* __restrict__ Out) {
  __shared__ u16 As[64 * 64];
  __shared__ u16 Bs[128 * 64];
  const int tile_n = blockIdx.x * 128, tm = blockIdx.y;
  const u16* Ap = Att + (size_t)tm * 65536;
  float* Cp = Out + (size_t)tm * 65536;

  const int t = threadIdx.x, lane = t & 63, wave = t >> 6;
  const int wm = (wave >> 1) * 32, wn = (wave & 1) * 64;
  const int row16 = lane & 15, quad = lane >> 4;
  const int l8 = lane >> 3;
  const int cswz = (lane & 7) ^ l8;

  f32x4 acc[2][4] = {};

  for (int k0 = 0; k0 < 1024; k0 += 64) {
    __syncthreads();
#pragma unroll
    for (int j = 0; j < 2; ++j) {
      int r = wave * 16 + j * 8 + l8;
      gload_lds16(Ap + (size_t)r * 1024 + k0 + cswz * 8,
                  &As[wave * 1024 + j * 512]);
    }
#pragma unroll
    for (int j = 0; j < 4; ++j) {
      int r = wave * 32 + j * 8 + l8;
      gload_lds16(WoT + (size_t)(tile_n + r) * 1024 + k0 + cswz * 8,
                  &Bs[wave * 2048 + j * 512]);
    }
    __syncthreads();

#pragma unroll
    for (int kb = 0; kb < 2; ++kb) {
      bf16x8 a_frag[2], b_frag[4];
#pragma unroll
      for (int i = 0; i < 2; ++i)
        a_frag[i] = *(const bf16x8*)&As[swz(wm + i * 16 + row16, kb * 4 + quad)];
#pragma unroll
      for (int j = 0; j < 4; ++j)
        b_frag[j] = *(const bf16x8*)&Bs[swz(wn + j * 16 + row16, kb * 4 + quad)];
#pragma unroll
      for (int i = 0; i < 2; ++i)
#pragma unroll
        for (int j = 0; j < 4; ++j)
          acc[i][j] = __builtin_amdgcn_mfma_f32_16x16x32_bf16(
              a_frag[i], b_frag[j], acc[i][j], 0, 0, 0);
    }
  }

#pragma unroll
  for (int j = 0; j < 4; ++j) {
    int n = tile_n + wn + j * 16 + row16;
    float bb = bo[n];
#pragma unroll
    for (int i = 0; i < 2; ++i) {
      int m0 = wm + i * 16 + quad * 4;
#pragma unroll
      for (int r = 0; r < 4; ++r)
        Cp[(size_t)(m0 + r) * 1024 + n] = acc[i][j][r] + bb;
    }
  }
}

// ---------------------------------------------------------------------------
// MFMA attention tile (unchanged from R9): block = (b, h, 32 s), ~35 KB LDS.
// ---------------------------------------------------------------------------
#define QS   0
#define KPS  2304
#define KFS  4608
#define KWS  6912
#define VTS  11008
#define SMT  15104

__global__ __launch_bounds__(256) void attn_tile(const u16* __restrict__ Qp,
                                                 const u16* __restrict__ Kp,
                                                 const u16* __restrict__ VpT,
                                                 const u16* __restrict__ Vd,
                                                 const float* __restrict__ bk,
                                                 const float* __restrict__ bv,
                                                 u16* __restrict__ Att) {
  __shared__ u16 sm[SMT];
  __shared__ float smP[32 * 36];

  const int t = threadIdx.x;
  const int bid = blockIdx.x;
  const int s0 = (bid & 63) * 32;
  const int h  = (bid >> 6) & 15;
  const int b  = bid >> 10;
  const int lane = t & 63, wave = t >> 6;
  const int row16 = lane & 15, quad = lane >> 4;
  const int hcol = h * 64;

  { int w = t >> 3, oct = t & 7;
    *(uint4*)&sm[QS + w * 72 + oct * 8] =
        *(const uint4*)(Qp + (size_t)(s0 + w) * 1024 + hcol + oct * 8); }
  { int r = t >> 3, oct = t & 7;
    *(uint4*)&sm[KPS + r * 72 + oct * 8] =
        *(const uint4*)(Kp + (size_t)(6144 + s0 + r) * 1024 + hcol + oct * 8);
    *(uint4*)&sm[KFS + r * 72 + oct * 8] =
        *(const uint4*)(Kp + (size_t)(4096 + s0 + r) * 1024 + hcol + oct * 8); }

  const bool boundary = (s0 == 0) || (s0 == 2016);
  if (!boundary) {
#pragma unroll
    for (int i = 0; i < 2; ++i) {
      int task = i * 256 + t;
      int w = task >> 3, oct = task & 7;
      gload_lds16(Kp + (size_t)(b * 2048 + s0 + w - 16) * 1024 + hcol + oct * 8,
                  &sm[KWS + (i * 256 + wave * 64) * 8]);
      int e = w;
      gload_lds16(VpT + (size_t)(hcol + e) * 4096 + (b * 2048 + s0 - 16) + oct * 8,
                  &sm[VTS + (i * 256 + wave * 64) * 8]);
    }
  } else {
#pragma unroll
    for (int i = 0; i < 2; ++i) {
      int task = i * 256 + t;
      int w = task >> 3, oct = task & 7;
      int g = s0 + w - 16;
      uint4 kv;
      if ((unsigned)g < 2048u)
        kv = *(const uint4*)(Kp + (size_t)(b * 2048 + g) * 1024 + hcol + oct * 8);
      else
        kv = pack8(*(const float4*)(bk + hcol + oct * 8),
                   *(const float4*)(bk + hcol + oct * 8 + 4));
      *(uint4*)&sm[KWS + w * 64 + oct * 8] = kv;

      int e = w;
      int g0 = s0 + oct * 8 - 16;
      uint4 vv;
      if (g0 >= 0 && g0 + 7 < 2048)
        vv = *(const uint4*)(VpT + (size_t)(hcol + e) * 4096 + (b * 2048 + g0));
      else {
        u16 hb = f2bf(bv[hcol + e]);
        u32 pp = (u32)hb | ((u32)hb << 16);
        vv = make_uint4(pp, pp, pp, pp);
      }
      *(uint4*)&sm[VTS + e * 64 + oct * 8] = vv;
    }
  }
  __syncthreads();

  {
    f32x4 accS[2] = {};
#pragma unroll
    for (int kc = 0; kc < 2; ++kc) {
      bf16x8 bf_ = *(const bf16x8*)&sm[KWS + (wave * 16 + row16) * 64 + kc * 32 + quad * 8];
#pragma unroll
      for (int mi = 0; mi < 2; ++mi) {
        bf16x8 af = *(const bf16x8*)&sm[QS + (mi * 16 + row16) * 72 + kc * 32 + quad * 8];
        accS[mi] = __builtin_amdgcn_mfma_f32_16x16x32_bf16(af, bf_, accS[mi], 0, 0, 0);
      }
    }
#pragma unroll
    for (int mi = 0; mi < 2; ++mi)
#pragma unroll
      for (int r = 0; r < 4; ++r) {
        int s = mi * 16 + quad * 4 + r;
        int w = wave * 16 + row16;
        int d = w - s;
        if (d >= 1 && d <= 31) smP[s * 36 + d - 1] = accS[mi][r] * 0.125f;
      }
  }
  if (t < 64) {
    int s = t >> 1, which = t & 1;
    int base = (which == 0) ? KPS : KFS;
    float a = 0.f;
#pragma unroll
    for (int c = 0; c < 8; ++c)
      a += dot8(*(const uint4*)&sm[QS + s * 72 + c * 8],
                *(const uint4*)&sm[base + s * 72 + c * 8]);
    smP[s * 36 + 31 + which] = a * 0.125f;
  }
  __syncthreads();

  if (t < 32) {
    int s = t;
    float vals[33];
#pragma unroll
    for (int k = 0; k < 33; ++k) vals[k] = smP[s * 36 + k];
    float mx = -1e30f;
#pragma unroll
    for (int k = 0; k < 33; ++k) mx = fmaxf(mx, vals[k]);
    float sum = 0.f;
#pragma unroll
    for (int k = 0; k < 33; ++k) { vals[k] = __expf(vals[k] - mx); sum += vals[k]; }
    float inv = 1.f / sum;
    u32* prow = (u32*)&sm[QS + s * 72];
#pragma unroll
    for (int j = 0; j < 32; ++j) prow[j] = 0;
#pragma unroll
    for (int k = 0; k < 31; ++k)
      sm[QS + s * 72 + (s + 1 + k)] = f2bf(vals[k] * inv);
    smP[s * 36 + 33] = vals[31] * inv;
    smP[s * 36 + 34] = vals[32] * inv;
  }
  __syncthreads();

  {
    f32x4 accO[2] = {};
#pragma unroll
    for (int kc = 0; kc < 2; ++kc) {
      bf16x8 bf_ = *(const bf16x8*)&sm[VTS + (wave * 16 + row16) * 64 + kc * 32 + quad * 8];
#pragma unroll
      for (int mi = 0; mi < 2; ++mi) {
        bf16x8 af = *(const bf16x8*)&sm[QS + (mi * 16 + row16) * 72 + kc * 32 + quad * 8];
        accO[mi] = __builtin_amdgcn_mfma_f32_16x16x32_bf16(af, bf_, accO[mi], 0, 0, 0);
      }
    }
#pragma unroll
    for (int mi = 0; mi < 2; ++mi)
#pragma unroll
      for (int r = 0; r < 4; ++r) {
        int s = mi * 16 + quad * 4 + r;
        int e = wave * 16 + row16;
        float o = accO[mi][r]
                + smP[s * 36 + 33] * bf2f(Vd[(size_t)(2048 + s0 + s) * 1024 + hcol + e])
                + smP[s * 36 + 34] * bf2f(Vd[(size_t)(s0 + s) * 1024 + hcol + e]);
        Att[(size_t)(b * 2048 + s0 + s) * 1024 + hcol + e] = f2bf(o);
      }
  }
}

// ---------------------------------------------------------------------------
extern "C" void kernel_launch(void* const* d_in, const int* in_sizes, int n_in,
                              void* d_out, int out_size, void* d_ws, size_t ws_size,
                              hipStream_t stream) {
  (void)in_sizes; (void)n_in; (void)out_size; (void)ws_size;

  const float* x   = (const float*)d_in[0];
  const float* fsq = (const float*)d_in[1];
  const float* pos = (const float*)d_in[2];
  const float* Wq  = (const float*)d_in[3];
  const float* bq  = (const float*)d_in[4];
  const float* Wk  = (const float*)d_in[5];
  const float* bk  = (const float*)d_in[6];
  const float* Wv  = (const float*)d_in[7];
  const float* bv  = (const float*)d_in[8];
  const float* Wo  = (const float*)d_in[9];
  const float* bo  = (const float*)d_in[10];

  u16* ws = (u16*)d_ws;
  const size_t M1 = 1024 * 1024;
  u16* WqT  = ws + 0 * M1;   // 1M
  u16* WkT  = ws + 1 * M1;   // 1M
  u16* WvT  = ws + 2 * M1;   // 1M
  u16* WoT  = ws + 3 * M1;   // 1M
  u16* Qp   = ws + 4 * M1;   // 2M : 2048x1024
  u16* Kp   = ws + 6 * M1;   // 8M : 8192x1024 row-major
  u16* VpT  = ws + 14 * M1;  // 4M : 1024(n) x 4096(m, x-rows) TRANSPOSED
  u16* Vd   = ws + 18 * M1;  // 4M : 4096x1024 row-major (fsq-V; pos-V)
  u16* fsqb = ws + 22 * M1;  // 2M
  u16* posb = ws + 24 * M1;  // 2M
  u16* xb   = ws + 26 * M1;  // 4M : 4096x1024
  u16* Att  = ws + 22 * M1;  // 4M, aliases fsqb+posb (dead after proj_gemm)
  // peak 30M u16 = 60 MB

  prep<<<5120, 256, 0, stream>>>(x, fsq, pos, Wq, Wk, Wv, Wo,
                                 xb, fsqb, posb, WqT, WkT, WvT, WoT);

  proj_gemm<<<576, 512, 0, stream>>>(xb, fsqb, posb, WkT, WvT, WqT,
                                     bk, bv, bq, Kp, VpT, Vd, Qp);

  attn_tile<<<2048, 256, 0, stream>>>(Qp, Kp, VpT, Vd, bk, bv, Att);

  out_gemm<<<dim3(8, 64), 256, 0, stream>>>(Att, WoT, bo, (float*)d_out);
}

// Round 11
// 194.302 us; speedup vs baseline: 1.0363x; 1.0363x over previous
//
#include <hip/hip_runtime.h>

// ---------------------------------------------------------------------------
// IntraModalityEnhance — fp32 in/out, bf16 MFMA internals.
// B=2, S=2048, D=1024, H=16, HD=64, E=1024, W=31 (+pos,+fsq keys = 33).
//
//  prep       : ONE launch — x/fsq/pos -> bf16  +  Wq/Wk/Wv/Wo transposes
//  proj_gemm  : ONE launch, 576 blocks x 512 threads, BM=128 x BN=256 with
//               N = K-half || V-half (K and V share the A-tile).
//  attn_tile  : block=(b,h,32 s); DMA staging, MFMA QK^T/PV; softmax split
//               across 64 threads (pair shfl combine).
//  out_gemm   : BM=64, BN=128, BK=128 (half the barrier drains; 48 KB LDS
//               keeps 2 blocks/CU which is already the grid limit).
// ---------------------------------------------------------------------------

typedef __attribute__((ext_vector_type(8))) short bf16x8;
typedef __attribute__((ext_vector_type(4))) float f32x4;
typedef unsigned short u16;
typedef unsigned int u32;
typedef unsigned long long u64;

__device__ __forceinline__ float bf2f(u16 u) {
  union { u32 i; float f; } v; v.i = ((u32)u) << 16; return v.f;
}
__device__ __forceinline__ u16 f2bf(float f) {
  union { float f; u32 i; } v; v.f = f;
  u32 r = v.i + 0x7fffu + ((v.i >> 16) & 1u);
  return (u16)(r >> 16);
}
__device__ __forceinline__ float2 unpk(u32 u) {
  union { u32 i; float f; } lo, hi;
  lo.i = u << 16; hi.i = u & 0xffff0000u;
  return make_float2(lo.f, hi.f);
}
__device__ __forceinline__ float dot8(uint4 a, uint4 b) {
  float s = 0.f;
  { float2 x = unpk(a.x), y = unpk(b.x); s += x.x*y.x + x.y*y.y; }
  { float2 x = unpk(a.y), y = unpk(b.y); s += x.x*y.x + x.y*y.y; }
  { float2 x = unpk(a.z), y = unpk(b.z); s += x.x*y.x + x.y*y.y; }
  { float2 x = unpk(a.w), y = unpk(b.w); s += x.x*y.x + x.y*y.y; }
  return s;
}
__device__ __forceinline__ void gload_lds16(const u16* g, u16* l) {
  __builtin_amdgcn_global_load_lds((const __attribute__((address_space(1))) void*)(g),
                                   (__attribute__((address_space(3))) void*)(l),
                                   16, 0, 0);
}
__device__ __forceinline__ uint4 pack8(float4 a, float4 b) {
  union { u16 h[8]; uint4 q; } u;
  u.h[0] = f2bf(a.x); u.h[1] = f2bf(a.y); u.h[2] = f2bf(a.z); u.h[3] = f2bf(a.w);
  u.h[4] = f2bf(b.x); u.h[5] = f2bf(b.y); u.h[6] = f2bf(b.z); u.h[7] = f2bf(b.w);
  return u.q;
}

// ---------------------------------------------------------------------------
__device__ __forceinline__ void transpose_body(const float* src, u16* dst,
                                               int R, int C, int r0, int c0) {
  __shared__ u16 tile[64][72];
  int t = threadIdx.x;
#pragma unroll
  for (int i = 0; i < 16; ++i) {
    int idx = i * 256 + t;
    int r = idx >> 6, c = idx & 63;
    tile[r][c] = f2bf(src[(size_t)(r0 + r) * C + (c0 + c)]);
  }
  __syncthreads();
#pragma unroll
  for (int i = 0; i < 16; ++i) {
    int idx = i * 256 + t;
    int c = idx >> 6, r = idx & 63;
    dst[(size_t)(c0 + c) * R + (r0 + r)] = tile[r][c];
  }
}

// ONE launch: blocks 0..4095 convert x/fsq/pos; 4096..5119 transpose weights.
__global__ __launch_bounds__(256) void prep(const float* __restrict__ x,
                                            const float* __restrict__ fsq,
                                            const float* __restrict__ pos,
                                            const float* __restrict__ Wq,
                                            const float* __restrict__ Wk,
                                            const float* __restrict__ Wv,
                                            const float* __restrict__ Wo,
                                            u16* __restrict__ xb,
                                            u16* __restrict__ fsqb,
                                            u16* __restrict__ posb,
                                            u16* __restrict__ WqT,
                                            u16* __restrict__ WkT,
                                            u16* __restrict__ WvT,
                                            u16* __restrict__ WoT) {
  int bid = blockIdx.x;
  if (bid < 4096) {
    int i = bid * 256 + threadIdx.x;
    const float* src; u16* dst; int off;
    if (i < 524288)      { src = x;   dst = xb;   off = i; }
    else if (i < 786432) { src = fsq; dst = fsqb; off = i - 524288; }
    else                 { src = pos; dst = posb; off = i - 786432; }
    float4 a = ((const float4*)src)[2 * off];
    float4 b = ((const float4*)src)[2 * off + 1];
    ((uint4*)dst)[off] = pack8(a, b);
  } else {
    int id = bid - 4096;
    int z = id >> 8, rest = id & 255;
    int xx = rest & 15, yy = rest >> 4;
    if (z < 3) {
      const float* s = (z == 0) ? Wq : (z == 1) ? Wk : Wv;
      u16* d = (z == 0) ? WqT : (z == 1) ? WkT : WvT;
      size_t off = (size_t)xx * 65536;    // head * 1024 * 64
      transpose_body(s + off, d + off, 1024, 64, yy * 64, 0);
    } else {
      transpose_body(Wo, WoT, 1024, 1024, yy * 64, xx * 64);
    }
  }
}

// ---------------------------------------------------------------------------
__device__ __forceinline__ int swz(int R, int c) {   // BK=64: 8 chunks/row
  return (R * 8 + (c ^ (R & 7))) * 8;
}

// ---------------------------------------------------------------------------
// proj_gemm: 512 threads, BM=128 x BN=256 (N = K-half || V-half).  As R10.
// ---------------------------------------------------------------------------
__global__ __launch_bounds__(512) void proj_gemm(const u16* __restrict__ xb,
                                                 const u16* __restrict__ fsqb,
                                                 const u16* __restrict__ posb,
                                                 const u16* __restrict__ WkT,
                                                 const u16* __restrict__ WvT,
                                                 const u16* __restrict__ WqT,
                                                 const float* __restrict__ bk,
                                                 const float* __restrict__ bv,
                                                 const float* __restrict__ bq,
                                                 u16* __restrict__ Kp,
                                                 u16* __restrict__ VpT,
                                                 u16* __restrict__ Vd,
                                                 u16* __restrict__ Qp) {
  __shared__ u16 As[128 * 64];   // 16 KB
  __shared__ u16 Bs[256 * 64];   // 32 KB

  const int bid = blockIdx.x;
  const int t = threadIdx.x, lane = t & 63, wave = t >> 6;   // wave 0..7
  const int row16 = lane & 15, quad = lane >> 4;
  const int l8 = lane >> 3;
  const int cswz = (lane & 7) ^ l8;

  const u16 *Ap, *BTa, *BTb;
  const float *biasA, *biasB;
  u16 *C1, *C2rm;
  int c1_noff, c2_noff;
  bool c2_t = false;
  int tmb = 0;

  if (bid < 512) {
    int tm = bid >> 3, tn = bid & 7;
    if (tm < 32)      Ap = xb   + (size_t)tm * 131072;
    else if (tm < 48) Ap = fsqb + (size_t)(tm - 32) * 131072;
    else              Ap = posb + (size_t)(tm - 48) * 131072;
    BTa = WkT + (size_t)(tn * 128) * 1024;
    BTb = WvT + (size_t)(tn * 128) * 1024;
    biasA = bk; biasB = bv;
    C1 = Kp + (size_t)tm * 131072; c1_noff = tn * 128;
    c2_noff = tn * 128;
    if (tm < 32) { c2_t = true; tmb = tm * 128; C2rm = nullptr; }
    else         { C2rm = Vd + (size_t)(tm - 32) * 131072; }
  } else {
    int q = bid - 512;
    int tm = q >> 2, tn4 = q & 3;
    Ap  = fsqb + (size_t)tm * 131072;
    BTa = WqT + (size_t)(tn4 * 256) * 1024;
    BTb = WqT + (size_t)(tn4 * 256 + 128) * 1024;
    biasA = bq; biasB = bq;
    C1 = Qp + (size_t)tm * 131072;  c1_noff = tn4 * 256;
    C2rm = C1;                      c2_noff = tn4 * 256 + 128;
  }

  const int wm = (wave >> 2) * 64, wn = (wave & 3) * 64;
  f32x4 acc[4][4] = {};

  for (int k0 = 0; k0 < 1024; k0 += 64) {
    __syncthreads();
#pragma unroll
    for (int j = 0; j < 2; ++j) {
      int r = wave * 16 + j * 8 + l8;
      gload_lds16(Ap + (size_t)r * 1024 + k0 + cswz * 8,
                  &As[wave * 1024 + j * 512]);
    }
    const u16* Bsrc = (wave < 4) ? BTa : BTb;
    const int rb = (wave & 3) * 32;
#pragma unroll
    for (int j = 0; j < 4; ++j) {
      int r = rb + j * 8 + l8;
      gload_lds16(Bsrc + (size_t)r * 1024 + k0 + cswz * 8,
                  &Bs[wave * 2048 + j * 512]);
    }
    __syncthreads();

#pragma unroll
    for (int kb = 0; kb < 2; ++kb) {
      bf16x8 a_frag[4], b_frag[4];
#pragma unroll
      for (int i = 0; i < 4; ++i)
        a_frag[i] = *(const bf16x8*)&As[swz(wm + i * 16 + row16, kb * 4 + quad)];
#pragma unroll
      for (int j = 0; j < 4; ++j)
        b_frag[j] = *(const bf16x8*)&Bs[swz(wn + j * 16 + row16, kb * 4 + quad)];
#pragma unroll
      for (int i = 0; i < 4; ++i)
#pragma unroll
        for (int j = 0; j < 4; ++j)
          acc[i][j] = __builtin_amdgcn_mfma_f32_16x16x32_bf16(
              a_frag[i], b_frag[j], acc[i][j], 0, 0, 0);
    }
  }

  if (wn < 128) {
#pragma unroll
    for (int j = 0; j < 4; ++j) {
      int n = c1_noff + wn + j * 16 + row16;
      float bb = biasA[n];
#pragma unroll
      for (int i = 0; i < 4; ++i) {
        int m0 = wm + i * 16 + quad * 4;
#pragma unroll
        for (int r = 0; r < 4; ++r)
          C1[(size_t)(m0 + r) * 1024 + n] = f2bf(acc[i][j][r] + bb);
      }
    }
  } else if (c2_t) {
#pragma unroll
    for (int j = 0; j < 4; ++j) {
      int nv = c2_noff + (wn - 128) + j * 16 + row16;
      float bb = biasB[nv];
#pragma unroll
      for (int i = 0; i < 4; ++i) {
        int m0 = wm + i * 16 + quad * 4;
        union { u16 h[4]; u64 q; } o;
#pragma unroll
        for (int r = 0; r < 4; ++r) o.h[r] = f2bf(acc[i][j][r] + bb);
        *(u64*)(VpT + (size_t)nv * 4096 + tmb + m0) = o.q;
      }
    }
  } else {
#pragma unroll
    for (int j = 0; j < 4; ++j) {
      int nv = c2_noff + (wn - 128) + j * 16 + row16;
      float bb = biasB[nv];
#pragma unroll
      for (int i = 0; i < 4; ++i) {
        int m0 = wm + i * 16 + quad * 4;
#pragma unroll
        for (int r = 0; r < 4; ++r)
          C2rm[(size_t)(m0 + r) * 1024 + nv] = f2bf(acc[i][j][r] + bb);
      }
    }
  }
}

// ---------------------------------------------------------------------------
// out_gemm: BM=64, BN=128, BK=128.  16-chunk XOR swizzle (c ^ (r&15)); half
// the barrier drains vs BK=64.  48 KB LDS; grid 512 -> 2 blocks/CU (grid was
// already the co-residency limit, so no occupancy loss).
// ---------------------------------------------------------------------------
__global__ __launch_bounds__(256) void out_gemm(const u16* __restrict__ Att,
                                                const u16* __restrict__ WoT,
                                                const float* __restrict__ bo,
                                                float* __restrict__ Out) {
  __shared__ u16 As[64 * 128];    // 16 KB
  __shared__ u16 Bs[128 * 128];   // 32 KB
  const int tile_n = blockIdx.x * 128, tm = blockIdx.y;
  const u16* Ap = Att + (size_t)tm * 65536;
  float* Cp = Out + (size_t)tm * 65536;

  const int t = threadIdx.x, lane = t & 63, wave = t >> 6;
  const int wm = (wave >> 1) * 32, wn = (wave & 1) * 64;
  const int row16 = lane & 15, quad = lane >> 4;

  f32x4 acc[2][4] = {};

  for (int k0 = 0; k0 < 1024; k0 += 128) {
    __syncthreads();
    // A: 64 rows x 16 chunks = 1024 chunks; wave covers rows wave*16..+15
#pragma unroll
    for (int j = 0; j < 4; ++j) {
      int idx = wave * 256 + j * 64 + lane;
      int r = idx >> 4, c = (idx & 15) ^ (r & 15);
      gload_lds16(Ap + (size_t)r * 1024 + k0 + c * 8,
                  &As[wave * 2048 + j * 512]);
    }
    // B: 128 rows x 16 chunks = 2048 chunks; wave covers rows wave*32..+31
#pragma unroll
    for (int j = 0; j < 8; ++j) {
      int idx = wave * 512 + j * 64 + lane;
      int r = idx >> 4, c = (idx & 15) ^ (r & 15);
      gload_lds16(WoT + (size_t)(tile_n + r) * 1024 + k0 + c * 8,
                  &Bs[wave * 4096 + j * 512]);
    }
    __syncthreads();

#pragma unroll
    for (int kb = 0; kb < 4; ++kb) {
      bf16x8 a_frag[2], b_frag[4];
#pragma unroll
      for (int i = 0; i < 2; ++i) {
        int R = wm + i * 16 + row16, c = kb * 4 + quad;
        a_frag[i] = *(const bf16x8*)&As[(R * 16 + (c ^ (R & 15))) * 8];
      }
#pragma unroll
      for (int j = 0; j < 4; ++j) {
        int R = wn + j * 16 + row16, c = kb * 4 + quad;
        b_frag[j] = *(const bf16x8*)&Bs[(R * 16 + (c ^ (R & 15))) * 8];
      }
#pragma unroll
      for (int i = 0; i < 2; ++i)
#pragma unroll
        for (int j = 0; j < 4; ++j)
          acc[i][j] = __builtin_amdgcn_mfma_f32_16x16x32_bf16(
              a_frag[i], b_frag[j], acc[i][j], 0, 0, 0);
    }
  }

#pragma unroll
  for (int j = 0; j < 4; ++j) {
    int n = tile_n + wn + j * 16 + row16;
    float bb = bo[n];
#pragma unroll
    for (int i = 0; i < 2; ++i) {
      int m0 = wm + i * 16 + quad * 4;
#pragma unroll
      for (int r = 0; r < 4; ++r)
        Cp[(size_t)(m0 + r) * 1024 + n] = acc[i][j][r] + bb;
    }
  }
}

// ---------------------------------------------------------------------------
// MFMA attention tile: block = (b, h, 32 s), ~35 KB LDS.  Softmax split over
// 64 threads (lane pairs, shfl_xor combine).
// ---------------------------------------------------------------------------
#define QS   0
#define KPS  2304
#define KFS  4608
#define KWS  6912
#define VTS  11008
#define SMT  15104

__global__ __launch_bounds__(256) void attn_tile(const u16* __restrict__ Qp,
                                                 const u16* __restrict__ Kp,
                                                 const u16* __restrict__ VpT,
                                                 const u16* __restrict__ Vd,
                                                 const float* __restrict__ bk,
                                                 const float* __restrict__ bv,
                                                 u16* __restrict__ Att) {
  __shared__ u16 sm[SMT];
  __shared__ float smP[32 * 36];

  const int t = threadIdx.x;
  const int bid = blockIdx.x;
  const int s0 = (bid & 63) * 32;
  const int h  = (bid >> 6) & 15;
  const int b  = bid >> 10;
  const int lane = t & 63, wave = t >> 6;
  const int row16 = lane & 15, quad = lane >> 4;
  const int hcol = h * 64;

  { int w = t >> 3, oct = t & 7;
    *(uint4*)&sm[QS + w * 72 + oct * 8] =
        *(const uint4*)(Qp + (size_t)(s0 + w) * 1024 + hcol + oct * 8); }
  { int r = t >> 3, oct = t & 7;
    *(uint4*)&sm[KPS + r * 72 + oct * 8] =
        *(const uint4*)(Kp + (size_t)(6144 + s0 + r) * 1024 + hcol + oct * 8);
    *(uint4*)&sm[KFS + r * 72 + oct * 8] =
        *(const uint4*)(Kp + (size_t)(4096 + s0 + r) * 1024 + hcol + oct * 8); }

  const bool boundary = (s0 == 0) || (s0 == 2016);
  if (!boundary) {
#pragma unroll
    for (int i = 0; i < 2; ++i) {
      int task = i * 256 + t;
      int w = task >> 3, oct = task & 7;
      gload_lds16(Kp + (size_t)(b * 2048 + s0 + w - 16) * 1024 + hcol + oct * 8,
                  &sm[KWS + (i * 256 + wave * 64) * 8]);
      int e = w;
      gload_lds16(VpT + (size_t)(hcol + e) * 4096 + (b * 2048 + s0 - 16) + oct * 8,
                  &sm[VTS + (i * 256 + wave * 64) * 8]);
    }
  } else {
#pragma unroll
    for (int i = 0; i < 2; ++i) {
      int task = i * 256 + t;
      int w = task >> 3, oct = task & 7;
      int g = s0 + w - 16;
      uint4 kv;
      if ((unsigned)g < 2048u)
        kv = *(const uint4*)(Kp + (size_t)(b * 2048 + g) * 1024 + hcol + oct * 8);
      else
        kv = pack8(*(const float4*)(bk + hcol + oct * 8),
                   *(const float4*)(bk + hcol + oct * 8 + 4));
      *(uint4*)&sm[KWS + w * 64 + oct * 8] = kv;

      int e = w;
      int g0 = s0 + oct * 8 - 16;
      uint4 vv;
      if (g0 >= 0 && g0 + 7 < 2048)
        vv = *(const uint4*)(VpT + (size_t)(hcol + e) * 4096 + (b * 2048 + g0));
      else {
        u16 hb = f2bf(bv[hcol + e]);
        u32 pp = (u32)hb | ((u32)hb << 16);
        vv = make_uint4(pp, pp, pp, pp);
      }
      *(uint4*)&sm[VTS + e * 64 + oct * 8] = vv;
    }
  }
  __syncthreads();

  {
    f32x4 accS[2] = {};
#pragma unroll
    for (int kc = 0; kc < 2; ++kc) {
      bf16x8 bf_ = *(const bf16x8*)&sm[KWS + (wave * 16 + row16) * 64 + kc * 32 + quad * 8];
#pragma unroll
      for (int mi = 0; mi < 2; ++mi) {
        bf16x8 af = *(const bf16x8*)&sm[QS + (mi * 16 + row16) * 72 + kc * 32 + quad * 8];
        accS[mi] = __builtin_amdgcn_mfma_f32_16x16x32_bf16(af, bf_, accS[mi], 0, 0, 0);
      }
    }
#pragma unroll
    for (int mi = 0; mi < 2; ++mi)
#pragma unroll
      for (int r = 0; r < 4; ++r) {
        int s = mi * 16 + quad * 4 + r;
        int w = wave * 16 + row16;
        int d = w - s;
        if (d >= 1 && d <= 31) smP[s * 36 + d - 1] = accS[mi][r] * 0.125f;
      }
  }
  if (t < 64) {
    int s = t >> 1, which = t & 1;
    int base = (which == 0) ? KPS : KFS;
    float a = 0.f;
#pragma unroll
    for (int c = 0; c < 8; ++c)
      a += dot8(*(const uint4*)&sm[QS + s * 72 + c * 8],
                *(const uint4*)&sm[base + s * 72 + c * 8]);
    smP[s * 36 + 31 + which] = a * 0.125f;
  }
  __syncthreads();

  // ---- softmax: 64 threads, lane pair (2s, 2s+1) splits 33 keys 17/16 ----
  if (t < 64) {
    const int s = t >> 1, half = t & 1;
    const int kb_ = half * 17;          // 0 or 17
    float vals[17];
#pragma unroll
    for (int k = 0; k < 17; ++k) {
      int kk = kb_ + k;
      vals[k] = (kk < 33) ? smP[s * 36 + kk] : -1e30f;
    }
    float mx = -1e30f;
#pragma unroll
    for (int k = 0; k < 17; ++k) mx = fmaxf(mx, vals[k]);
    mx = fmaxf(mx, __shfl_xor(mx, 1, 64));
    float sum = 0.f;
#pragma unroll
    for (int k = 0; k < 17; ++k) { vals[k] = __expf(vals[k] - mx); sum += vals[k]; }
    sum += __shfl_xor(sum, 1, 64);
    const float inv = 1.f / sum;
    u32* prow = (u32*)&sm[QS + s * 72];
#pragma unroll
    for (int j = 0; j < 16; ++j) prow[half * 16 + j] = 0;   // zero cols 0..63
    // (same-wave LDS ops are ordered: zeros complete before band writes)
#pragma unroll
    for (int k = 0; k < 17; ++k) {
      int kk = kb_ + k;
      if (kk < 31)      sm[QS + s * 72 + (s + 1 + kk)] = f2bf(vals[k] * inv);
      else if (kk < 33) smP[s * 36 + 2 + kk] = vals[k] * inv;  // 31->33, 32->34
    }
  }
  __syncthreads();

  {
    f32x4 accO[2] = {};
#pragma unroll
    for (int kc = 0; kc < 2; ++kc) {
      bf16x8 bf_ = *(const bf16x8*)&sm[VTS + (wave * 16 + row16) * 64 + kc * 32 + quad * 8];
#pragma unroll
      for (int mi = 0; mi < 2; ++mi) {
        bf16x8 af = *(const bf16x8*)&sm[QS + (mi * 16 + row16) * 72 + kc * 32 + quad * 8];
        accO[mi] = __builtin_amdgcn_mfma_f32_16x16x32_bf16(af, bf_, accO[mi], 0, 0, 0);
      }
    }
#pragma unroll
    for (int mi = 0; mi < 2; ++mi)
#pragma unroll
      for (int r = 0; r < 4; ++r) {
        int s = mi * 16 + quad * 4 + r;
        int e = wave * 16 + row16;
        float o = accO[mi][r]
                + smP[s * 36 + 33] * bf2f(Vd[(size_t)(2048 + s0 + s) * 1024 + hcol + e])
                + smP[s * 36 + 34] * bf2f(Vd[(size_t)(s0 + s) * 1024 + hcol + e]);
        Att[(size_t)(b * 2048 + s0 + s) * 1024 + hcol + e] = f2bf(o);
      }
  }
}

// ---------------------------------------------------------------------------
extern "C" void kernel_launch(void* const* d_in, const int* in_sizes, int n_in,
                              void* d_out, int out_size, void* d_ws, size_t ws_size,
                              hipStream_t stream) {
  (void)in_sizes; (void)n_in; (void)out_size; (void)ws_size;

  const float* x   = (const float*)d_in[0];
  const float* fsq = (const float*)d_in[1];
  const float* pos = (const float*)d_in[2];
  const float* Wq  = (const float*)d_in[3];
  const float* bq  = (const float*)d_in[4];
  const float* Wk  = (const float*)d_in[5];
  const float* bk  = (const float*)d_in[6];
  const float* Wv  = (const float*)d_in[7];
  const float* bv  = (const float*)d_in[8];
  const float* Wo  = (const float*)d_in[9];
  const float* bo  = (const float*)d_in[10];

  u16* ws = (u16*)d_ws;
  const size_t M1 = 1024 * 1024;
  u16* WqT  = ws + 0 * M1;   // 1M
  u16* WkT  = ws + 1 * M1;   // 1M
  u16* WvT  = ws + 2 * M1;   // 1M
  u16* WoT  = ws + 3 * M1;   // 1M
  u16* Qp   = ws + 4 * M1;   // 2M : 2048x1024
  u16* Kp   = ws + 6 * M1;   // 8M : 8192x1024 row-major
  u16* VpT  = ws + 14 * M1;  // 4M : 1024(n) x 4096(m, x-rows) TRANSPOSED
  u16* Vd   = ws + 18 * M1;  // 4M : 4096x1024 row-major (fsq-V; pos-V)
  u16* fsqb = ws + 22 * M1;  // 2M
  u16* posb = ws + 24 * M1;  // 2M
  u16* xb   = ws + 26 * M1;  // 4M : 4096x1024
  u16* Att  = ws + 22 * M1;  // 4M, aliases fsqb+posb (dead after proj_gemm)
  // peak 30M u16 = 60 MB

  prep<<<5120, 256, 0, stream>>>(x, fsq, pos, Wq, Wk, Wv, Wo,
                                 xb, fsqb, posb, WqT, WkT, WvT, WoT);

  proj_gemm<<<576, 512, 0, stream>>>(xb, fsqb, posb, WkT, WvT, WqT,
                                     bk, bv, bq, Kp, VpT, Vd, Qp);

  attn_tile<<<2048, 256, 0, stream>>>(Qp, Kp, VpT, Vd, bk, bv, Att);

  out_gemm<<<dim3(8, 64), 256, 0, stream>>>(Att, WoT, bo, (float*)d_out);
}